// Round 9
// baseline (44.994 us; speedup 1.0000x reference)
//
#include <hip/hip_runtime.h>

// Problem constants (match reference)
#define B_ROWS   256
#define L_COLS   65536
#define SLICES   8
#define THREADS  256
#define NBLOCKS  (B_ROWS * SLICES)          // 2048 blocks = 8/CU, all resident
#define V_ROW    (L_COLS / 4)               // 16384 float4 per row
#define V_SLICE  (V_ROW / SLICES)           // 2048 float4 per slice
//
// Fused single kernel. Cross-block handoff WITHOUT release/acquire fences
// (R3 lesson: per-block buffer_wbl2/inv = +120us). Instead:
//   writer: global_store sc0 sc1 (write-through past non-coherent L2 to the
//           L3 coherent point) -> s_waitcnt vmcnt(0) -> RELAXED device-scope
//           fetch_add (atomics execute at the coherent point, no cache maint)
//   reader (last block): global_load sc0 sc1 (bypass L1/L2)
//
// Workspace layout (R8 lesson: ws_size is likely exactly 64 KiB — stay under):
//   [0,   64)                  counter (4B used, 64B pad)
//   [64,  64+32768)            recA[bid]: float4 {sp, st, spp, stt}
//   [32832, 32832+8192)        recB[bid]: float  {spt}   (row-contiguous x8)
//   total 41024 B < 65536 B.
// All inline-asm operands are clang ext_vector floats (R7 lesson).

typedef float v4f __attribute__((ext_vector_type(4)));

#define WS_RECA_OFF   64
#define WS_RECB_OFF   (64 + NBLOCKS * 16)

#define GLOAD(dst, ptr) \
    asm volatile("global_load_dwordx4 %0, %1, off" : "=v"(dst) : "v"(ptr) : "memory")
#define GLOAD_SC(dst, ptr) \
    asm volatile("global_load_dwordx4 %0, %1, off sc0 sc1" : "=v"(dst) : "v"(ptr) : "memory")
#define GSTORE4_SC(ptr, val) \
    asm volatile("global_store_dwordx4 %0, %1, off sc0 sc1" :: "v"(ptr), "v"(val) : "memory")
#define GSTORE1_SC(ptr, val) \
    asm volatile("global_store_dword %0, %1, off sc0 sc1" :: "v"(ptr), "v"(val) : "memory")
#define WAITV(n) do { \
    asm volatile("s_waitcnt vmcnt(" #n ")" ::: "memory"); \
    __builtin_amdgcn_sched_barrier(0); } while (0)

__global__ __launch_bounds__(THREADS, 4)
void signal_loss_fused(const v4f* __restrict__ pred,
                       const v4f* __restrict__ trgt,
                       char* __restrict__ ws,
                       float* __restrict__ out)
{
    const int bid   = blockIdx.x;
    const int row   = bid >> 3;             // / SLICES
    const int slice = bid & (SLICES - 1);
    const size_t base = (size_t)row * V_ROW + (size_t)slice * V_SLICE + threadIdx.x;
    const v4f* P = pred + base;
    const v4f* T = trgt + base;

    unsigned int* counter = (unsigned int*)ws;
    v4f*   recA = (v4f*)(ws + WS_RECA_OFF);
    float* recB = (float*)(ws + WS_RECB_OFF);

    v4f a0, a1, at0, at1;   // batch A
    v4f b0, b1, bt0, bt1;   // batch B
    v4f c0, c1, ct0, ct1;   // batch C
    v4f d0, d1, dt0, dt1;   // batch D

    // Issue all 16 loads back-to-back (256 B/lane in flight).
    GLOAD(a0,  P + 0 * THREADS); GLOAD(a1,  P + 1 * THREADS);
    GLOAD(at0, T + 0 * THREADS); GLOAD(at1, T + 1 * THREADS);
    GLOAD(b0,  P + 2 * THREADS); GLOAD(b1,  P + 3 * THREADS);
    GLOAD(bt0, T + 2 * THREADS); GLOAD(bt1, T + 3 * THREADS);
    GLOAD(c0,  P + 4 * THREADS); GLOAD(c1,  P + 5 * THREADS);
    GLOAD(ct0, T + 4 * THREADS); GLOAD(ct1, T + 5 * THREADS);
    GLOAD(d0,  P + 6 * THREADS); GLOAD(d1,  P + 7 * THREADS);
    GLOAD(dt0, T + 6 * THREADS); GLOAD(dt1, T + 7 * THREADS);

    float sp = 0.f, st = 0.f, spp = 0.f, stt = 0.f, spt = 0.f;

#define ACC1(p, t) do { \
    sp  += (p).x + (p).y + (p).z + (p).w; \
    st  += (t).x + (t).y + (t).z + (t).w; \
    spp += (p).x*(p).x + (p).y*(p).y + (p).z*(p).z + (p).w*(p).w; \
    stt += (t).x*(t).x + (t).y*(t).y + (t).z*(t).z + (t).w*(t).w; \
    spt += (p).x*(t).x + (p).y*(t).y + (p).z*(t).z + (p).w*(t).w; } while (0)

    WAITV(12); ACC1(a0, at0); ACC1(a1, at1);
    WAITV(8);  ACC1(b0, bt0); ACC1(b1, bt1);
    WAITV(4);  ACC1(c0, ct0); ACC1(c1, ct1);
    WAITV(0);  ACC1(d0, dt0); ACC1(d1, dt1);
#undef ACC1

    // Wave-64 reduce via shfl_down (5 values)
    #pragma unroll
    for (int off = 32; off >= 1; off >>= 1) {
        sp  += __shfl_down(sp,  off);
        st  += __shfl_down(st,  off);
        spp += __shfl_down(spp, off);
        stt += __shfl_down(stt, off);
        spt += __shfl_down(spt, off);
    }

    __shared__ float red[4][5];
    __shared__ unsigned int lastflag;
    const int lane = threadIdx.x & 63;
    const int wave = threadIdx.x >> 6;
    if (lane == 0) {
        red[wave][0] = sp;  red[wave][1] = st;  red[wave][2] = spp;
        red[wave][3] = stt; red[wave][4] = spt;
    }
    __syncthreads();
    if (threadIdx.x == 0) {
        v4f rec;
        rec.x = red[0][0] + red[1][0] + red[2][0] + red[3][0];  // sum p
        rec.y = red[0][1] + red[1][1] + red[2][1] + red[3][1];  // sum t
        rec.z = red[0][2] + red[1][2] + red[2][2] + red[3][2];  // sum p^2
        rec.w = red[0][3] + red[1][3] + red[2][3] + red[3][3];  // sum t^2
        const float sptv = red[0][4] + red[1][4] + red[2][4] + red[3][4];
        v4f*   dstA = recA + bid;
        float* dstB = recB + bid;
        GSTORE4_SC(dstA, rec);
        GSTORE1_SC(dstB, sptv);
        asm volatile("s_waitcnt vmcnt(0)" ::: "memory");   // stores at coherent point
        const unsigned int old = __hip_atomic_fetch_add(
            counter, 1u, __ATOMIC_RELAXED, __HIP_MEMORY_SCOPE_AGENT);
        lastflag = (old == (unsigned int)(NBLOCKS - 1)) ? 1u : 0u;
    }
    __syncthreads();
    if (!lastflag) return;

    // ---- Last block finalizes. One thread per row. ----
    {
        const int r = threadIdx.x;
        const v4f* rpA = recA + (size_t)r * SLICES;
        const v4f* rpB = (const v4f*)(recB + (size_t)r * SLICES); // 8 floats = 2 v4f
        v4f l0,l1,l2,l3,l4,l5,l6,l7;   // recA of each slice
        v4f q0,q1;                      // recB: spt of 8 slices
        GLOAD_SC(l0, rpA + 0); GLOAD_SC(l1, rpA + 1);
        GLOAD_SC(l2, rpA + 2); GLOAD_SC(l3, rpA + 3);
        GLOAD_SC(l4, rpA + 4); GLOAD_SC(l5, rpA + 5);
        GLOAD_SC(l6, rpA + 6); GLOAD_SC(l7, rpA + 7);
        GLOAD_SC(q0, rpB + 0); GLOAD_SC(q1, rpB + 1);
        WAITV(0);

        double s0=0.0, s1=0.0, s2=0.0, s3=0.0, s4=0.0;
#define ACCF(l) do { \
        s0 += (double)(l).x; s1 += (double)(l).y; \
        s2 += (double)(l).z; s3 += (double)(l).w; } while (0)
        ACCF(l0); ACCF(l1); ACCF(l2); ACCF(l3);
        ACCF(l4); ACCF(l5); ACCF(l6); ACCF(l7);
#undef ACCF
        s4 = (double)q0.x + (double)q0.y + (double)q0.z + (double)q0.w
           + (double)q1.x + (double)q1.y + (double)q1.z + (double)q1.w;

        const double n = (double)L_COLS;
        const double num   = s4 - s0 * s1 / n;        // sum(xm*ym)
        const double den_t = s3 - s1 * s1 / n;        // sum(xm^2), xm from y_true
        const double den_p = s2 - s0 * s0 / n;        // sum(ym^2), ym from y_pred
        double den = sqrt(den_t * den_p);
        den = den > 1e-8 ? den : 1e-8;
        double romr = 1.0 - num / den;                // 1 - r for this row
        double sd   = s2 + s3 - 2.0 * s4;             // sum((p-t)^2) for this row

        #pragma unroll
        for (int off = 32; off >= 1; off >>= 1) {
            romr += __shfl_down(romr, off);
            sd   += __shfl_down(sd,   off);
        }
        __shared__ double w0[4], w1[4];
        if (lane == 0) { w0[wave] = romr; w1[wave] = sd; }
        __syncthreads();
        if (threadIdx.x == 0) {
            const double corr = (w0[0] + w0[1] + w0[2] + w0[3]) / (double)B_ROWS;
            const double mse  = (w1[0] + w1[1] + w1[2] + w1[3])
                              / ((double)B_ROWS * (double)L_COLS);
            out[0] = (float)(0.7 * mse + 0.3 * corr);
        }
    }
}

extern "C" void kernel_launch(void* const* d_in, const int* in_sizes, int n_in,
                              void* d_out, int out_size, void* d_ws, size_t ws_size,
                              hipStream_t stream) {
    const v4f* pred = (const v4f*)d_in[0];  // y_pred
    const v4f* trgt = (const v4f*)d_in[1];  // y_true
    char* ws   = (char*)d_ws;               // 41 KiB used, see layout above
    float* out = (float*)d_out;

    (void)hipMemsetAsync(ws, 0, sizeof(unsigned int), stream);  // counter = 0
    signal_loss_fused<<<NBLOCKS, THREADS, 0, stream>>>(pred, trgt, ws, out);
}

// Round 10
// 33.485 us; speedup vs baseline: 1.3437x; 1.3437x over previous
//
#include <hip/hip_runtime.h>

// Problem constants (match reference)
#define B_ROWS   256
#define L_COLS   65536
#define SLICES   8
#define THREADS  256
#define NBLOCKS  (B_ROWS * SLICES)          // 2048 blocks = 8/CU, all resident
#define V_ROW    (L_COLS / 4)               // 16384 float4 per row
#define V_SLICE  (V_ROW / SLICES)           // 2048 float4 per slice
#define BUCKETS    64
#define BUCKET_SZ  (NBLOCKS / BUCKETS)      // 32 blocks per bucket
//
// Fused single kernel, handoff WITHOUT release/acquire fences (R3 lesson:
// per-block buffer_wbl2/inv = +120us) and WITHOUT a single shared counter
// (R9 lesson: 2048 same-address atomics drain ~19us serially; blocks wait
// on the return value). Two-level counter tree: 64 bucket counters in
// separate 64B lines (32 contenders each) + 1 master (64 contenders).
//   writer: global_store sc0 sc1 (write-through past non-coherent L2 to the
//           L3 coherent point) -> s_waitcnt vmcnt(0) -> RELAXED device-scope
//           fetch_add on bucket; last-in-bucket bumps master.
//   reader (last block): global_load sc0 sc1 (bypass L1/L2).
//
// Workspace layout (ws_size is 64 KiB — stay under):
//   [0, 4160)        counters: master @0, bucket[i] @ 64*(i+1)
//   [4224, 36992)    recA[bid]: float4 {sp, st, spp, stt}
//   [36992, 45184)   recB[bid]: float {spt}  (row-contiguous x8, 16B aligned)
// All inline-asm operands are clang ext_vector floats (R7 lesson).

typedef float v4f __attribute__((ext_vector_type(4)));

#define WS_CNT_BYTES  4160
#define WS_RECA_OFF   4224
#define WS_RECB_OFF   (WS_RECA_OFF + NBLOCKS * 16)

#define GLOAD(dst, ptr) \
    asm volatile("global_load_dwordx4 %0, %1, off" : "=v"(dst) : "v"(ptr) : "memory")
#define GLOAD_SC(dst, ptr) \
    asm volatile("global_load_dwordx4 %0, %1, off sc0 sc1" : "=v"(dst) : "v"(ptr) : "memory")
#define GSTORE4_SC(ptr, val) \
    asm volatile("global_store_dwordx4 %0, %1, off sc0 sc1" :: "v"(ptr), "v"(val) : "memory")
#define GSTORE1_SC(ptr, val) \
    asm volatile("global_store_dword %0, %1, off sc0 sc1" :: "v"(ptr), "v"(val) : "memory")
#define WAITV(n) do { \
    asm volatile("s_waitcnt vmcnt(" #n ")" ::: "memory"); \
    __builtin_amdgcn_sched_barrier(0); } while (0)

__global__ __launch_bounds__(THREADS, 4)
void signal_loss_fused(const v4f* __restrict__ pred,
                       const v4f* __restrict__ trgt,
                       char* __restrict__ ws,
                       float* __restrict__ out)
{
    const int bid   = blockIdx.x;
    const int row   = bid >> 3;             // / SLICES
    const int slice = bid & (SLICES - 1);
    const size_t base = (size_t)row * V_ROW + (size_t)slice * V_SLICE + threadIdx.x;
    const v4f* P = pred + base;
    const v4f* T = trgt + base;

    unsigned int* master = (unsigned int*)ws;
    unsigned int* bucket = (unsigned int*)(ws + 64 * (1 + (bid / BUCKET_SZ)));
    v4f*   recA = (v4f*)(ws + WS_RECA_OFF);
    float* recB = (float*)(ws + WS_RECB_OFF);

    v4f a0, a1, at0, at1;   // batch A
    v4f b0, b1, bt0, bt1;   // batch B
    v4f c0, c1, ct0, ct1;   // batch C
    v4f d0, d1, dt0, dt1;   // batch D

    // Issue all 16 loads back-to-back (256 B/lane in flight).
    GLOAD(a0,  P + 0 * THREADS); GLOAD(a1,  P + 1 * THREADS);
    GLOAD(at0, T + 0 * THREADS); GLOAD(at1, T + 1 * THREADS);
    GLOAD(b0,  P + 2 * THREADS); GLOAD(b1,  P + 3 * THREADS);
    GLOAD(bt0, T + 2 * THREADS); GLOAD(bt1, T + 3 * THREADS);
    GLOAD(c0,  P + 4 * THREADS); GLOAD(c1,  P + 5 * THREADS);
    GLOAD(ct0, T + 4 * THREADS); GLOAD(ct1, T + 5 * THREADS);
    GLOAD(d0,  P + 6 * THREADS); GLOAD(d1,  P + 7 * THREADS);
    GLOAD(dt0, T + 6 * THREADS); GLOAD(dt1, T + 7 * THREADS);

    float sp = 0.f, st = 0.f, spp = 0.f, stt = 0.f, spt = 0.f;

#define ACC1(p, t) do { \
    sp  += (p).x + (p).y + (p).z + (p).w; \
    st  += (t).x + (t).y + (t).z + (t).w; \
    spp += (p).x*(p).x + (p).y*(p).y + (p).z*(p).z + (p).w*(p).w; \
    stt += (t).x*(t).x + (t).y*(t).y + (t).z*(t).z + (t).w*(t).w; \
    spt += (p).x*(t).x + (p).y*(t).y + (p).z*(t).z + (p).w*(t).w; } while (0)

    WAITV(12); ACC1(a0, at0); ACC1(a1, at1);
    WAITV(8);  ACC1(b0, bt0); ACC1(b1, bt1);
    WAITV(4);  ACC1(c0, ct0); ACC1(c1, ct1);
    WAITV(0);  ACC1(d0, dt0); ACC1(d1, dt1);
#undef ACC1

    // Wave-64 reduce via shfl_down (5 values)
    #pragma unroll
    for (int off = 32; off >= 1; off >>= 1) {
        sp  += __shfl_down(sp,  off);
        st  += __shfl_down(st,  off);
        spp += __shfl_down(spp, off);
        stt += __shfl_down(stt, off);
        spt += __shfl_down(spt, off);
    }

    __shared__ float red[4][5];
    __shared__ unsigned int lastflag;
    const int lane = threadIdx.x & 63;
    const int wave = threadIdx.x >> 6;
    if (lane == 0) {
        red[wave][0] = sp;  red[wave][1] = st;  red[wave][2] = spp;
        red[wave][3] = stt; red[wave][4] = spt;
    }
    __syncthreads();
    if (threadIdx.x == 0) {
        v4f rec;
        rec.x = red[0][0] + red[1][0] + red[2][0] + red[3][0];  // sum p
        rec.y = red[0][1] + red[1][1] + red[2][1] + red[3][1];  // sum t
        rec.z = red[0][2] + red[1][2] + red[2][2] + red[3][2];  // sum p^2
        rec.w = red[0][3] + red[1][3] + red[2][3] + red[3][3];  // sum t^2
        const float sptv = red[0][4] + red[1][4] + red[2][4] + red[3][4];
        v4f*   dstA = recA + bid;
        float* dstB = recB + bid;
        GSTORE4_SC(dstA, rec);
        GSTORE1_SC(dstB, sptv);
        asm volatile("s_waitcnt vmcnt(0)" ::: "memory");   // records at coherent point
        unsigned int lf = 0;
        const unsigned int ob = __hip_atomic_fetch_add(
            bucket, 1u, __ATOMIC_RELAXED, __HIP_MEMORY_SCOPE_AGENT);
        if (ob == (unsigned int)(BUCKET_SZ - 1)) {
            const unsigned int om = __hip_atomic_fetch_add(
                master, 1u, __ATOMIC_RELAXED, __HIP_MEMORY_SCOPE_AGENT);
            lf = (om == (unsigned int)(BUCKETS - 1)) ? 1u : 0u;
        }
        lastflag = lf;
    }
    __syncthreads();
    if (!lastflag) return;

    // ---- Last block finalizes. One thread per row. ----
    {
        const int r = threadIdx.x;
        const v4f* rpA = recA + (size_t)r * SLICES;
        const v4f* rpB = (const v4f*)(recB + (size_t)r * SLICES); // 8 floats = 2 v4f
        v4f l0,l1,l2,l3,l4,l5,l6,l7;   // recA of each slice
        v4f q0,q1;                      // recB: spt of 8 slices
        GLOAD_SC(l0, rpA + 0); GLOAD_SC(l1, rpA + 1);
        GLOAD_SC(l2, rpA + 2); GLOAD_SC(l3, rpA + 3);
        GLOAD_SC(l4, rpA + 4); GLOAD_SC(l5, rpA + 5);
        GLOAD_SC(l6, rpA + 6); GLOAD_SC(l7, rpA + 7);
        GLOAD_SC(q0, rpB + 0); GLOAD_SC(q1, rpB + 1);
        WAITV(0);

        double s0=0.0, s1=0.0, s2=0.0, s3=0.0, s4=0.0;
#define ACCF(l) do { \
        s0 += (double)(l).x; s1 += (double)(l).y; \
        s2 += (double)(l).z; s3 += (double)(l).w; } while (0)
        ACCF(l0); ACCF(l1); ACCF(l2); ACCF(l3);
        ACCF(l4); ACCF(l5); ACCF(l6); ACCF(l7);
#undef ACCF
        s4 = (double)q0.x + (double)q0.y + (double)q0.z + (double)q0.w
           + (double)q1.x + (double)q1.y + (double)q1.z + (double)q1.w;

        const double n = (double)L_COLS;
        const double num   = s4 - s0 * s1 / n;        // sum(xm*ym)
        const double den_t = s3 - s1 * s1 / n;        // sum(xm^2), xm from y_true
        const double den_p = s2 - s0 * s0 / n;        // sum(ym^2), ym from y_pred
        double den = sqrt(den_t * den_p);
        den = den > 1e-8 ? den : 1e-8;
        double romr = 1.0 - num / den;                // 1 - r for this row
        double sd   = s2 + s3 - 2.0 * s4;             // sum((p-t)^2) for this row

        #pragma unroll
        for (int off = 32; off >= 1; off >>= 1) {
            romr += __shfl_down(romr, off);
            sd   += __shfl_down(sd,   off);
        }
        __shared__ double w0[4], w1[4];
        if (lane == 0) { w0[wave] = romr; w1[wave] = sd; }
        __syncthreads();
        if (threadIdx.x == 0) {
            const double corr = (w0[0] + w0[1] + w0[2] + w0[3]) / (double)B_ROWS;
            const double mse  = (w1[0] + w1[1] + w1[2] + w1[3])
                              / ((double)B_ROWS * (double)L_COLS);
            out[0] = (float)(0.7 * mse + 0.3 * corr);
        }
    }
}

extern "C" void kernel_launch(void* const* d_in, const int* in_sizes, int n_in,
                              void* d_out, int out_size, void* d_ws, size_t ws_size,
                              hipStream_t stream) {
    const v4f* pred = (const v4f*)d_in[0];  // y_pred
    const v4f* trgt = (const v4f*)d_in[1];  // y_true
    char* ws   = (char*)d_ws;               // 45184 B used, see layout above
    float* out = (float*)d_out;

    (void)hipMemsetAsync(ws, 0, WS_CNT_BYTES, stream);  // zero counter tree
    signal_loss_fused<<<NBLOCKS, THREADS, 0, stream>>>(pred, trgt, ws, out);
}

// Round 11
// 26.928 us; speedup vs baseline: 1.6709x; 1.2435x over previous
//
#include <hip/hip_runtime.h>

// Problem constants (match reference)
#define B_ROWS   256
#define L_COLS   65536
#define SLICES   8
#define THREADS  256
#define NBLOCKS  (B_ROWS * SLICES)          // 2048 blocks = 8/CU, all resident
#define V_ROW    (L_COLS / 4)               // 16384 float4 per row
#define V_SLICE  (V_ROW / SLICES)           // 2048 float4 per slice
//
// Two-kernel structure (fusion refuted: R3=150us fence storm, R9=45us atomic
// drain, R10=33.5us store-drain tail; split=28.8us). Streaming loads carry
// 'nt' (non-temporal): 134MB single-pass stream thrashes the 4MB/XCD L2s
// (16.8MB/XCD, zero reuse) — nt skips L2 allocation, removing evict/fill
// churn from the read path.
// Per thread: 8 float4 per input = 16 loads, ALL issued up front via inline
// asm (register-pinned), consumed in 4 batches via counted s_waitcnt
// vmcnt(12/8/4/0) + sched_barrier(0) (rule #18). 256 B/lane in flight.
// sum((p-t)^2) = spp + stt - 2*spt reconstructed in f64 at finalize.

typedef float v4f __attribute__((ext_vector_type(4)));

#define GLOAD_NT(dst, ptr) \
    asm volatile("global_load_dwordx4 %0, %1, off nt" : "=v"(dst) : "v"(ptr) : "memory")
#define WAITV(n) do { \
    asm volatile("s_waitcnt vmcnt(" #n ")" ::: "memory"); \
    __builtin_amdgcn_sched_barrier(0); } while (0)

__global__ __launch_bounds__(THREADS, 4)
void signal_loss_partials(const v4f* __restrict__ pred,
                          const v4f* __restrict__ trgt,
                          float* __restrict__ ws)
{
    const int bid   = blockIdx.x;
    const int row   = bid >> 3;             // / SLICES
    const int slice = bid & (SLICES - 1);
    const size_t base = (size_t)row * V_ROW + (size_t)slice * V_SLICE + threadIdx.x;
    const v4f* P = pred + base;
    const v4f* T = trgt + base;

    v4f a0, a1, at0, at1;   // batch A
    v4f b0, b1, bt0, bt1;   // batch B
    v4f c0, c1, ct0, ct1;   // batch C
    v4f d0, d1, dt0, dt1;   // batch D

    // Issue all 16 loads back-to-back (256 B/lane in flight), nt = no L2 alloc.
    GLOAD_NT(a0,  P + 0 * THREADS); GLOAD_NT(a1,  P + 1 * THREADS);
    GLOAD_NT(at0, T + 0 * THREADS); GLOAD_NT(at1, T + 1 * THREADS);
    GLOAD_NT(b0,  P + 2 * THREADS); GLOAD_NT(b1,  P + 3 * THREADS);
    GLOAD_NT(bt0, T + 2 * THREADS); GLOAD_NT(bt1, T + 3 * THREADS);
    GLOAD_NT(c0,  P + 4 * THREADS); GLOAD_NT(c1,  P + 5 * THREADS);
    GLOAD_NT(ct0, T + 4 * THREADS); GLOAD_NT(ct1, T + 5 * THREADS);
    GLOAD_NT(d0,  P + 6 * THREADS); GLOAD_NT(d1,  P + 7 * THREADS);
    GLOAD_NT(dt0, T + 6 * THREADS); GLOAD_NT(dt1, T + 7 * THREADS);

    float sp = 0.f, st = 0.f, spp = 0.f, stt = 0.f, spt = 0.f;

#define ACC1(p, t) do { \
    sp  += (p).x + (p).y + (p).z + (p).w; \
    st  += (t).x + (t).y + (t).z + (t).w; \
    spp += (p).x*(p).x + (p).y*(p).y + (p).z*(p).z + (p).w*(p).w; \
    stt += (t).x*(t).x + (t).y*(t).y + (t).z*(t).z + (t).w*(t).w; \
    spt += (p).x*(t).x + (p).y*(t).y + (p).z*(t).z + (p).w*(t).w; } while (0)

    WAITV(12); ACC1(a0, at0); ACC1(a1, at1);
    WAITV(8);  ACC1(b0, bt0); ACC1(b1, bt1);
    WAITV(4);  ACC1(c0, ct0); ACC1(c1, ct1);
    WAITV(0);  ACC1(d0, dt0); ACC1(d1, dt1);
#undef ACC1

    // Wave-64 reduce via shfl_down (5 values)
    #pragma unroll
    for (int off = 32; off >= 1; off >>= 1) {
        sp  += __shfl_down(sp,  off);
        st  += __shfl_down(st,  off);
        spp += __shfl_down(spp, off);
        stt += __shfl_down(stt, off);
        spt += __shfl_down(spt, off);
    }

    __shared__ float red[4][5];
    const int lane = threadIdx.x & 63;
    const int wave = threadIdx.x >> 6;
    if (lane == 0) {
        red[wave][0] = sp;  red[wave][1] = st;  red[wave][2] = spp;
        red[wave][3] = stt; red[wave][4] = spt;
    }
    __syncthreads();
    if (threadIdx.x == 0) {
        // Records padded to 8 floats so finalize reads 2xfloat4 per record.
        float* dst = ws + (size_t)bid * 8;
        #pragma unroll
        for (int k = 0; k < 5; ++k)
            dst[k] = red[0][k] + red[1][k] + red[2][k] + red[3][k];
        dst[5] = 0.f; dst[6] = 0.f; dst[7] = 0.f;
    }
}

__global__ __launch_bounds__(B_ROWS)
void signal_loss_finalize(const float4* __restrict__ ws4,
                          float* __restrict__ out)
{
    const int row = threadIdx.x;  // one thread per row, 256 threads

    // Issue all 16 float4 loads up front (independent, one latency shot).
    float4 lo[SLICES], hi[SLICES];
    #pragma unroll
    for (int sl = 0; sl < SLICES; ++sl) {
        const size_t rec = ((size_t)row * SLICES + sl) * 2;  // 2 float4 per record
        lo[sl] = ws4[rec + 0];
        hi[sl] = ws4[rec + 1];
    }

    double s0=0.0, s1=0.0, s2=0.0, s3=0.0, s4=0.0;
    #pragma unroll
    for (int sl = 0; sl < SLICES; ++sl) {
        s0 += (double)lo[sl].x;  // sum p
        s1 += (double)lo[sl].y;  // sum t
        s2 += (double)lo[sl].z;  // sum p^2
        s3 += (double)lo[sl].w;  // sum t^2
        s4 += (double)hi[sl].x;  // sum p*t
    }

    const double n = (double)L_COLS;
    const double num   = s4 - s0 * s1 / n;        // sum(xm*ym)
    const double den_t = s3 - s1 * s1 / n;        // sum(xm^2), xm from y_true
    const double den_p = s2 - s0 * s0 / n;        // sum(ym^2), ym from y_pred
    double den = sqrt(den_t * den_p);
    den = den > 1e-8 ? den : 1e-8;
    double romr = 1.0 - num / den;                // 1 - r for this row
    double sd   = s2 + s3 - 2.0 * s4;             // sum((p-t)^2) for this row

    #pragma unroll
    for (int off = 32; off >= 1; off >>= 1) {
        romr += __shfl_down(romr, off);
        sd   += __shfl_down(sd,   off);
    }
    __shared__ double w0[4], w1[4];
    const int lane = threadIdx.x & 63;
    const int wave = threadIdx.x >> 6;
    if (lane == 0) { w0[wave] = romr; w1[wave] = sd; }
    __syncthreads();
    if (threadIdx.x == 0) {
        const double corr = (w0[0] + w0[1] + w0[2] + w0[3]) / (double)B_ROWS;
        const double mse  = (w1[0] + w1[1] + w1[2] + w1[3])
                          / ((double)B_ROWS * (double)L_COLS);
        out[0] = (float)(0.7 * mse + 0.3 * corr);
    }
}

extern "C" void kernel_launch(void* const* d_in, const int* in_sizes, int n_in,
                              void* d_out, int out_size, void* d_ws, size_t ws_size,
                              hipStream_t stream) {
    const v4f* pred = (const v4f*)d_in[0];  // y_pred
    const v4f* trgt = (const v4f*)d_in[1];  // y_true
    float* ws  = (float*)d_ws;              // NBLOCKS*8 floats = 64 KiB partials
    float* out = (float*)d_out;

    signal_loss_partials<<<NBLOCKS, THREADS, 0, stream>>>(pred, trgt, ws);
    signal_loss_finalize<<<1, B_ROWS, 0, stream>>>((const float4*)ws, out);
}